// Round 4
// baseline (71.344 us; speedup 1.0000x reference)
//
#include <hip/hip_runtime.h>
#include <hip/hip_bf16.h>

typedef __bf16 bf16x8 __attribute__((ext_vector_type(8)));
typedef __bf16 bf16x4 __attribute__((ext_vector_type(4)));
typedef float  f32x4  __attribute__((ext_vector_type(4)));
typedef float  f32x2  __attribute__((ext_vector_type(2)));

#define MFMA16(A, B, C) __builtin_amdgcn_mfma_f32_16x16x32_bf16(A, B, C, 0, 0, 0)
// write->read fence on wave-private LDS (compiler ordering + DS drain)
#define FENCE_WAIT() do { asm volatile("s_waitcnt lgkmcnt(0)" ::: "memory"); \
                          __builtin_amdgcn_sched_barrier(0); } while (0)

// ---- load s for a 32-edge pair directly into MFMA B-fragments (bf16) ----
template <bool FULL>
__device__ __forceinline__ void load_pair_s(const float* __restrict__ s, int ebase,
                                            int lrow, int lg, int E, bf16x8 sf[2][2])
{
  #pragma unroll
  for (int q = 0; q < 2; ++q) {
    int er = ebase + q * 16 + lrow;
    if (!FULL) er = er < E ? er : E - 1;
    const float* sp = s + (size_t)er * 64 + lg * 8;
    f32x4 a0 = *(const f32x4*)(sp);
    f32x4 a1 = *(const f32x4*)(sp + 4);
    f32x4 a2 = *(const f32x4*)(sp + 32);
    f32x4 a3 = *(const f32x4*)(sp + 36);
    #pragma unroll
    for (int i = 0; i < 4; ++i) {
      sf[q][0][i] = (__bf16)a0[i]; sf[q][0][i + 4] = (__bf16)a1[i];
      sf[q][1][i] = (__bf16)a2[i]; sf[q][1][i + 4] = (__bf16)a3[i];
    }
  }
}

// ---- GEMM1 for one pair: hT = relu(W1^T @ s^T + b1) -> 4KB wave-private LDS ----
__device__ __forceinline__ void gemm1_to_lds(char* hbuf, const unsigned short* w1t,
                                             const bf16x8 sf[2][2], const f32x4 bias1[4],
                                             int lrow, int lg)
{
  #pragma unroll
  for (int jt = 0; jt < 4; ++jt) {
    const int j = jt * 16 + lrow;
    int wb0 = (j << 7) + ((lg * 8) << 1);      wb0 ^= (j & 7) << 4;
    int wb1 = (j << 7) + ((32 + lg * 8) << 1); wb1 ^= (j & 7) << 4;
    bf16x8 wf0 = *(const bf16x8*)((const char*)w1t + wb0);
    bf16x8 wf1 = *(const bf16x8*)((const char*)w1t + wb1);
    #pragma unroll
    for (int q = 0; q < 2; ++q) {
      f32x4 acc = bias1[jt];
      acc = MFMA16(wf0, sf[q][0], acc);
      acc = MFMA16(wf1, sf[q][1], acc);
      bf16x4 hv;
      #pragma unroll
      for (int r = 0; r < 4; ++r) hv[r] = (__bf16)fmaxf(acc[r], 0.f);
      // h[edge = q*16+lrow][hid = jt*16+lg*4 .. +3], swizzled
      int byte = ((q * 16 + lrow) << 7) + ((jt * 16 + lg * 4) << 1);
      byte ^= (lrow & 7) << 4;
      *(bf16x4*)(hbuf + byte) = hv;
    }
  }
}

// ---- GEMM2 + in-register complex epilogue for one pair ----
template <bool FULL>
__device__ __forceinline__ void gemm2_epilogue(const char* hbuf, const unsigned short* w2t,
                                               const float* __restrict__ x,
                                               const f32x4 bias2[2],
                                               float* __restrict__ out,
                                               int ebase, int lrow, int lg, int E)
{
  // x loads issued first (deep slack before use)
  f32x4 xv[2];
  #pragma unroll
  for (int q = 0; q < 2; ++q) {
    int er = ebase + q * 16 + lrow;
    if (!FULL) er = er < E ? er : E - 1;
    xv[q] = *(const f32x4*)(x + (size_t)er * 8 + (lg & 1) * 4);
  }
  bf16x8 hf[2][2];
  #pragma unroll
  for (int q = 0; q < 2; ++q)
    #pragma unroll
    for (int c = 0; c < 2; ++c) {
      int byte = ((q * 16 + lrow) << 7) + ((c * 32 + lg * 8) << 1);
      byte ^= (lrow & 7) << 4;
      hf[q][c] = *(const bf16x8*)(hbuf + byte);
    }
  bf16x8 w2f[2][2];
  #pragma unroll
  for (int dt = 0; dt < 2; ++dt)
    #pragma unroll
    for (int c = 0; c < 2; ++c) {
      int d = dt * 16 + lrow;
      int byte = (d << 7) + ((c * 32 + lg * 8) << 1);
      byte ^= (d & 7) << 4;
      w2f[dt][c] = *(const bf16x8*)((const char*)w2t + byte);
    }
  // pin the h-reads above any later h-writes (next pair reuses the buffer)
  __builtin_amdgcn_sched_barrier(0);

  #pragma unroll
  for (int q = 0; q < 2; ++q) {
    f32x4 xe = xv[q];
    float qr[2], qi[2];
    #pragma unroll
    for (int dt = 0; dt < 2; ++dt) {
      f32x4 a = bias2[dt];
      a = MFMA16(w2f[dt][0], hf[q][0], a);
      a = MFMA16(w2f[dt][1], hf[q][1], a);
      // lane holds w[e][d = dt*16+lg*4+r]; o=2dt+(lg>>1), p=2(lg&1)+(r>>1), c=r&1
      float pr = xe[0] * a[0] - xe[1] * a[1] + xe[2] * a[2] - xe[3] * a[3];
      float pi = xe[0] * a[1] + xe[1] * a[0] + xe[2] * a[3] + xe[3] * a[2];
      qr[dt] = pr + __shfl_xor(pr, 16, 64);
      qi[dt] = pi + __shfl_xor(pi, 16, 64);
    }
    const int sel = lg & 1;
    const int o = (lg >> 1) + 2 * sel;
    const float vr = sel ? qr[1] : qr[0];
    const float vi = sel ? qi[1] : qi[0];
    const int e = ebase + q * 16 + lrow;
    if (FULL || e < E) {
      f32x2 v2 = {vr, vi};
      *(f32x2*)(out + (size_t)e * 8 + o * 2) = v2;
    }
  }
}

__global__ __launch_bounds__(256, 4) void so2_fused_kernel(
    const float* __restrict__ x, const float* __restrict__ s,
    const float* __restrict__ W1, const float* __restrict__ b1v,
    const float* __restrict__ W2, const float* __restrict__ b2v,
    float* __restrict__ out, int E)
{
  __shared__ unsigned short lds_w1t[64 * 64];  // W1^T [j][k] bf16, XOR-swizzled
  __shared__ unsigned short lds_w2t[32 * 64];  // W2^T [d][k] bf16, XOR-swizzled
  __shared__ char lds_h[4][4096];              // per-wave h for 32 edges, swizzled

  const int tid  = threadIdx.x;
  const int wid  = tid >> 6;
  const int lane = tid & 63;
  const int lrow = lane & 15;
  const int lg   = lane >> 4;

  // ---- stage weights ONCE per (persistent) block ----
  #pragma unroll
  for (int it = 0; it < 4; ++it) {
    int i = (it * 256 + tid) * 4;            // 4 consecutive floats, same k row
    f32x4 v = *(const f32x4*)(W1 + i);
    int k = i >> 6, j = i & 63;
    #pragma unroll
    for (int q = 0; q < 4; ++q) {
      int byte = ((j + q) << 7) + (k << 1);
      byte ^= ((j + q) & 7) << 4;
      *(unsigned short*)((char*)lds_w1t + byte) =
          __builtin_bit_cast(unsigned short, (__bf16)v[q]);
    }
  }
  #pragma unroll
  for (int it = 0; it < 2; ++it) {
    int i = (it * 256 + tid) * 4;            // i = k*32 + d
    f32x4 v = *(const f32x4*)(W2 + i);
    int k = i >> 5, d = i & 31;
    #pragma unroll
    for (int q = 0; q < 4; ++q) {
      int byte = ((d + q) << 7) + (k << 1);
      byte ^= ((d + q) & 7) << 4;
      *(unsigned short*)((char*)lds_w2t + byte) =
          __builtin_bit_cast(unsigned short, (__bf16)v[q]);
    }
  }
  f32x4 bias1[4], bias2[2];
  #pragma unroll
  for (int jt = 0; jt < 4; ++jt) bias1[jt] = *(const f32x4*)(b1v + jt * 16 + lg * 4);
  #pragma unroll
  for (int dt = 0; dt < 2; ++dt) bias2[dt] = *(const f32x4*)(b2v + dt * 16 + lg * 4);
  __syncthreads();

  char* hbuf = lds_h[wid];
  const int nChunks = (E + 255) >> 8;

  for (int c = blockIdx.x; c < nChunks; c += gridDim.x) {
    const int web = c * 256 + wid * 64;
    if (web >= E) continue;                  // wave-uniform; no barrier in loop
    if (web + 64 <= E) {
      // ---- fast path: no clamps, no store guards ----
      bf16x8 sf0[2][2], sf1[2][2];
      load_pair_s<true>(s, web, lrow, lg, E, sf0);
      gemm1_to_lds(hbuf, lds_w1t, sf0, bias1, lrow, lg);
      load_pair_s<true>(s, web + 32, lrow, lg, E, sf1);  // in flight across fence
      FENCE_WAIT();
      gemm2_epilogue<true>(hbuf, lds_w2t, x, bias2, out, web, lrow, lg, E);
      gemm1_to_lds(hbuf, lds_w1t, sf1, bias1, lrow, lg);
      FENCE_WAIT();
      gemm2_epilogue<true>(hbuf, lds_w2t, x, bias2, out, web + 32, lrow, lg, E);
    } else {
      bf16x8 sf0[2][2], sf1[2][2];
      load_pair_s<false>(s, web, lrow, lg, E, sf0);
      gemm1_to_lds(hbuf, lds_w1t, sf0, bias1, lrow, lg);
      load_pair_s<false>(s, web + 32, lrow, lg, E, sf1);
      FENCE_WAIT();
      gemm2_epilogue<false>(hbuf, lds_w2t, x, bias2, out, web, lrow, lg, E);
      gemm1_to_lds(hbuf, lds_w1t, sf1, bias1, lrow, lg);
      FENCE_WAIT();
      gemm2_epilogue<false>(hbuf, lds_w2t, x, bias2, out, web + 32, lrow, lg, E);
    }
  }
}

extern "C" void kernel_launch(void* const* d_in, const int* in_sizes, int n_in,
                              void* d_out, int out_size, void* d_ws, size_t ws_size,
                              hipStream_t stream) {
  const float* x  = (const float*)d_in[0];
  const float* s  = (const float*)d_in[1];
  const float* W1 = (const float*)d_in[2];
  const float* b1 = (const float*)d_in[3];
  const float* W2 = (const float*)d_in[4];
  const float* b2 = (const float*)d_in[5];
  float* out = (float*)d_out;
  const int E = in_sizes[0] / 8;               // x is (E, 4, 2)
  const int nChunks = (E + 255) / 256;
  const int blocks = nChunks < 1024 ? nChunks : 1024;  // 4 persistent blocks/CU
  so2_fused_kernel<<<blocks, 256, 0, stream>>>(x, s, W1, b1, W2, b2, out, E);
}

// Round 5
// 64.966 us; speedup vs baseline: 1.0982x; 1.0982x over previous
//
#include <hip/hip_runtime.h>
#include <hip/hip_bf16.h>

typedef __bf16 bf16x8 __attribute__((ext_vector_type(8)));
typedef __bf16 bf16x4 __attribute__((ext_vector_type(4)));
typedef float  f32x4  __attribute__((ext_vector_type(4)));
typedef float  f32x2  __attribute__((ext_vector_type(2)));

#define MFMA16(A, B, C) __builtin_amdgcn_mfma_f32_16x16x32_bf16(A, B, C, 0, 0, 0)
// h-write -> h-read ordering + DS drain (wave-private buffer)
#define FENCE_WAIT() do { asm volatile("s_waitcnt lgkmcnt(0)" ::: "memory"); \
                          __builtin_amdgcn_sched_barrier(0); } while (0)
// compiler-only memory fence (no instruction): stops TBAA-based reordering
#define FENCE_COMPILER() asm volatile("" ::: "memory")

// One wave = 256 contiguous edges = 16 tiles of 16 edges, 1-deep pipelined.
__global__ __launch_bounds__(256, 4) void so2_fused_kernel(
    const float* __restrict__ x, const float* __restrict__ s,
    const float* __restrict__ W1, const float* __restrict__ b1v,
    const float* __restrict__ W2, const float* __restrict__ b2v,
    float* __restrict__ out, int E)
{
  __shared__ unsigned short lds_w1t[64 * 64];  // W1^T [j][k] bf16, XOR-swizzled
  __shared__ unsigned short lds_w2t[32 * 64];  // W2^T [d][k] bf16, XOR-swizzled
  __shared__ char lds_h[4][2048];              // per-wave h for ONE 16-edge tile

  const int tid  = threadIdx.x;
  const int wid  = tid >> 6;
  const int lane = tid & 63;
  const int lrow = lane & 15;
  const int lg   = lane >> 4;

  // ---- biases straight to registers (loop-invariant) ----
  f32x4 bias1[4], bias2[2];
  #pragma unroll
  for (int jt = 0; jt < 4; ++jt) bias1[jt] = *(const f32x4*)(b1v + jt * 16 + lg * 4);
  #pragma unroll
  for (int dt = 0; dt < 2; ++dt) bias2[dt] = *(const f32x4*)(b2v + dt * 16 + lg * 4);

  // ---- stage weights once per block (bf16, transposed, XOR-swizzled) ----
  #pragma unroll
  for (int it = 0; it < 4; ++it) {
    int i = (it * 256 + tid) * 4;            // 4 consecutive floats, same k row
    f32x4 v = *(const f32x4*)(W1 + i);
    int k = i >> 6, j = i & 63;
    #pragma unroll
    for (int q = 0; q < 4; ++q) {
      int byte = ((j + q) << 7) + (k << 1);
      byte ^= ((j + q) & 7) << 4;
      *(unsigned short*)((char*)lds_w1t + byte) =
          __builtin_bit_cast(unsigned short, (__bf16)v[q]);
    }
  }
  #pragma unroll
  for (int it = 0; it < 2; ++it) {
    int i = (it * 256 + tid) * 4;            // i = k*32 + d
    f32x4 v = *(const f32x4*)(W2 + i);
    int k = i >> 5, d = i & 31;
    #pragma unroll
    for (int q = 0; q < 4; ++q) {
      int byte = ((d + q) << 7) + (k << 1);
      byte ^= ((d + q) & 7) << 4;
      *(unsigned short*)((char*)lds_w2t + byte) =
          __builtin_bit_cast(unsigned short, (__bf16)v[q]);
    }
  }
  __syncthreads();

  // ---- hoist W2^T fragments to registers (loop-invariant, 16 VGPR) ----
  bf16x8 w2f[2][2];
  #pragma unroll
  for (int dt = 0; dt < 2; ++dt)
    #pragma unroll
    for (int c = 0; c < 2; ++c) {
      int d = dt * 16 + lrow;
      int byte = (d << 7) + ((c * 32 + lg * 8) << 1);
      byte ^= (d & 7) << 4;
      w2f[dt][c] = *(const bf16x8*)((const char*)lds_w2t + byte);
    }

  const int wbase = blockIdx.x * 1024 + wid * 256;
  const int rem = E - wbase;
  const int nt = rem <= 0 ? 0 : (rem >= 256 ? 16 : ((rem + 15) >> 4));
  if (nt == 0) return;

  char* hbuf = lds_h[wid];

  // ---- prefetch tile 0 ----
  f32x4 sN[4];
  f32x4 xN;
  {
    int er = wbase + lrow; er = er < E ? er : E - 1;
    const float* sp = s + (size_t)er * 64 + lg * 8;
    sN[0] = *(const f32x4*)(sp);
    sN[1] = *(const f32x4*)(sp + 4);
    sN[2] = *(const f32x4*)(sp + 32);
    sN[3] = *(const f32x4*)(sp + 36);
    xN = *(const f32x4*)(x + (size_t)er * 8 + (lg & 1) * 4);
  }

  for (int t = 0; t < nt; ++t) {
    const int ebase = wbase + t * 16;

    // consume prefetched tile: convert s to bf16 B-fragments
    bf16x8 sf0, sf1;
    #pragma unroll
    for (int i = 0; i < 4; ++i) {
      sf0[i] = (__bf16)sN[0][i]; sf0[i + 4] = (__bf16)sN[1][i];
      sf1[i] = (__bf16)sN[2][i]; sf1[i + 4] = (__bf16)sN[3][i];
    }
    const f32x4 xe = xN;

    // issue next tile's loads NOW (in flight across all compute below)
    {
      int er = ebase + 16 + lrow; er = er < E ? er : E - 1;
      const float* sp = s + (size_t)er * 64 + lg * 8;
      sN[0] = *(const f32x4*)(sp);
      sN[1] = *(const f32x4*)(sp + 4);
      sN[2] = *(const f32x4*)(sp + 32);
      sN[3] = *(const f32x4*)(sp + 36);
      xN = *(const f32x4*)(x + (size_t)er * 8 + (lg & 1) * 4);
    }

    // ---- GEMM1: hT = relu(W1^T @ s^T + b1) -> 2KB wave-private LDS ----
    #pragma unroll
    for (int jt = 0; jt < 4; ++jt) {
      const int j = jt * 16 + lrow;
      int wb0 = (j << 7) + ((lg * 8) << 1);      wb0 ^= (j & 7) << 4;
      int wb1 = (j << 7) + ((32 + lg * 8) << 1); wb1 ^= (j & 7) << 4;
      bf16x8 wf0 = *(const bf16x8*)((const char*)lds_w1t + wb0);
      bf16x8 wf1 = *(const bf16x8*)((const char*)lds_w1t + wb1);
      f32x4 acc = bias1[jt];
      acc = MFMA16(wf0, sf0, acc);
      acc = MFMA16(wf1, sf1, acc);
      bf16x4 hv;
      #pragma unroll
      for (int r = 0; r < 4; ++r) hv[r] = (__bf16)fmaxf(acc[r], 0.f);
      // h[edge=lrow][hid = jt*16 + lg*4 .. +3], swizzled
      int byte = (lrow << 7) + ((jt * 16 + lg * 4) << 1);
      byte ^= (lrow & 7) << 4;
      *(bf16x4*)(hbuf + byte) = hv;
    }

    FENCE_WAIT();

    // ---- GEMM2: wT = W2^T @ hT + b2 (registers), then complex epilogue ----
    bf16x8 hf0, hf1;
    {
      int b0 = (lrow << 7) + ((lg * 8) << 1);      b0 ^= (lrow & 7) << 4;
      int b1 = (lrow << 7) + ((32 + lg * 8) << 1); b1 ^= (lrow & 7) << 4;
      hf0 = *(const bf16x8*)(hbuf + b0);
      hf1 = *(const bf16x8*)(hbuf + b1);
    }
    FENCE_COMPILER();  // pin h-reads above next iteration's h-writes

    float qr[2], qi[2];
    #pragma unroll
    for (int dt = 0; dt < 2; ++dt) {
      f32x4 a = bias2[dt];
      a = MFMA16(w2f[dt][0], hf0, a);
      a = MFMA16(w2f[dt][1], hf1, a);
      // lane holds w[e=lrow][d = dt*16+lg*4+r]; o=2dt+(lg>>1), p=2(lg&1)+(r>>1)
      float pr = xe[0] * a[0] - xe[1] * a[1] + xe[2] * a[2] - xe[3] * a[3];
      float pi = xe[0] * a[1] + xe[1] * a[0] + xe[2] * a[3] + xe[3] * a[2];
      qr[dt] = pr + __shfl_xor(pr, 16, 64);
      qi[dt] = pi + __shfl_xor(pi, 16, 64);
    }
    const int sel = lg & 1;
    const int o = (lg >> 1) + 2 * sel;
    const float vr = sel ? qr[1] : qr[0];
    const float vi = sel ? qi[1] : qi[0];
    const int e = ebase + lrow;
    if (e < E) {
      f32x2 v2 = {vr, vi};
      *(f32x2*)(out + (size_t)e * 8 + o * 2) = v2;
    }
  }
}

extern "C" void kernel_launch(void* const* d_in, const int* in_sizes, int n_in,
                              void* d_out, int out_size, void* d_ws, size_t ws_size,
                              hipStream_t stream) {
  const float* x  = (const float*)d_in[0];
  const float* s  = (const float*)d_in[1];
  const float* W1 = (const float*)d_in[2];
  const float* b1 = (const float*)d_in[3];
  const float* W2 = (const float*)d_in[4];
  const float* b2 = (const float*)d_in[5];
  float* out = (float*)d_out;
  const int E = in_sizes[0] / 8;                 // x is (E, 4, 2)
  const int blocks = (E + 1023) / 1024;          // 1024 edges/block; all resident
  so2_fused_kernel<<<blocks, 256, 0, stream>>>(x, s, W1, b1, W2, b2, out, E);
}